// Round 18
// baseline (510.905 us; speedup 1.0000x reference)
//
#include <hip/hip_runtime.h>
#include <hip/hip_bf16.h>

#define DEVFN static __device__ __forceinline__

typedef __attribute__((ext_vector_type(8))) __bf16 bf16x8;
typedef __attribute__((ext_vector_type(4))) float f32x4;
typedef __attribute__((ext_vector_type(16))) float f32x16;
typedef __attribute__((ext_vector_type(4))) unsigned short u16x4;

#define MFMA16(a, b, c) __builtin_amdgcn_mfma_f32_16x16x32_bf16(a, b, c, 0, 0, 0)
#define MFMA32(a, b, c) __builtin_amdgcn_mfma_f32_32x32x16_bf16(a, b, c, 0, 0, 0)

// async global->LDS, 16B per lane; dest is wave-uniform base + lane*16
DEVFN void gload16(const void* g, void* l) {
  __builtin_amdgcn_global_load_lds((const __attribute__((address_space(1))) void*)g,
                                   (__attribute__((address_space(3))) void*)l, 16, 0, 0);
}

DEVFN void vwait8() { asm volatile("s_waitcnt vmcnt(8)" ::: "memory"); __builtin_amdgcn_sched_barrier(0); }
DEVFN void vwait4() { asm volatile("s_waitcnt vmcnt(4)" ::: "memory"); __builtin_amdgcn_sched_barrier(0); }
DEVFN void vwait0() { asm volatile("s_waitcnt vmcnt(0)" ::: "memory"); __builtin_amdgcn_sched_barrier(0); }
DEVFN void bar()    { __builtin_amdgcn_s_barrier(); }
// raw barrier + sched fence: safe ONLY when no cross-wave ds_write handoff
DEVFN void barsched() { __builtin_amdgcn_s_barrier(); __builtin_amdgcn_sched_barrier(0); }

// pack two f32 -> dword of 2 bf16 (compiler emits cvt_pk)
DEVFN unsigned pk2(float a, float b) {
  union { __bf16 h[2]; unsigned u; } z;
  z.h[0] = (__bf16)a; z.h[1] = (__bf16)b;
  return z.u;
}

// assemble one PV A-fragment from 4 literal-index packs (branch-free selects)
DEVFN bf16x8 mk_pa(bool h1, unsigned lo0, unsigned lo1, unsigned hi0, unsigned hi1) {
  const unsigned sA = h1 ? hi0 : lo0, sB = h1 ? hi1 : lo1;
  const unsigned cA = h1 ? lo0 : hi0, cB = h1 ? lo1 : hi1;
  const unsigned rA = (unsigned)__shfl_xor((int)cA, 32);
  const unsigned rB = (unsigned)__shfl_xor((int)cB, 32);
  union { unsigned u[4]; bf16x8 v; } z;
  z.u[0] = h1 ? rA : sA; z.u[1] = h1 ? rB : sB;
  z.u[2] = h1 ? sA : rA; z.u[3] = h1 ? sB : rB;
  return z.v;
}

// ---------------- f32 -> bf16 convert (vectorized) ----------------
__global__ __launch_bounds__(256) void cvt_f32_bf16(const float* __restrict__ in,
                                                    __bf16* __restrict__ out) {
  size_t i = ((size_t)blockIdx.x * 256 + threadIdx.x) * 8;
  f32x4 a = *(const f32x4*)(in + i);
  f32x4 b = *(const f32x4*)(in + i + 4);
  bf16x8 u;
  u[0] = (__bf16)a[0]; u[1] = (__bf16)a[1]; u[2] = (__bf16)a[2]; u[3] = (__bf16)a[3];
  u[4] = (__bf16)b[0]; u[5] = (__bf16)b[1]; u[6] = (__bf16)b[2]; u[7] = (__bf16)b[3];
  *(bf16x8*)(out + i) = u;
}

// ---------------- transpose f32 [K][N] -> bf16 [N][K] ----------------
__global__ __launch_bounds__(256) void transpose_w(const float* __restrict__ in,
                                                   __bf16* __restrict__ out,
                                                   int K, int N) {
  __shared__ float tile[32][33];
  const int t = threadIdx.x, tx = t & 31, ty = t >> 5;
  const int n0 = blockIdx.x * 32, k0 = blockIdx.y * 32;
#pragma unroll
  for (int r = 0; r < 4; r++)
    tile[ty + r * 8][tx] = in[(size_t)(k0 + ty + r * 8) * N + n0 + tx];
  __syncthreads();
#pragma unroll
  for (int r = 0; r < 4; r++)
    out[(size_t)(n0 + ty + r * 8) * K + k0 + tx] = (__bf16)tile[tx][ty + r * 8];
}

// ===== 256x256 bf16 GEMM: 4-phase lockstep + PHASE-AHEAD operand reads =====
// Reads for phase i+1 issue under phase i's MFMA (same barriers/stages as R17).
#define QK_SCALE 0.12751745f  // (1/sqrt(128)) * log2(e)

DEVFN void stage_tile(const __bf16* gx, size_t Kst, int t, __bf16* ldst,
                      int rr, int gsw, int w) {
#pragma unroll
  for (int j = 0; j < 4; j++)
    gload16(gx + (size_t)(j * 64 + rr) * Kst + (size_t)t * 64 + gsw,
            ldst + j * 4096 + w * 512);
}

DEVFN void stage_chunk(const __bf16* gx, size_t Kst, int t, __bf16* ldst, int j,
                       int rr, int gsw, int w) {
  gload16(gx + (size_t)(j * 64 + rr) * Kst + (size_t)t * 64 + gsw,
          ldst + j * 4096 + w * 512);
}

// Per K-tile: 4 phases x 16 MFMA; stage of tile t+2 spread across phases.
// Prefetched reads (bHi in ph1, aHi in ph2) are consumed by the NEXT phase's
// MFMAs -> compiler lgkm waits drain them before the barrier that precedes
// any stage overwriting their rows (safety audited per-chunk).
DEVFN void tile_step(__bf16* la, __bf16* lb, f32x4 (&acc)[8][4],
                     const __bf16* ga, const __bf16* gb, size_t Kst, int t, int NT,
                     int rr, int gsw, int w, int wr, int wc, int lg, int li) {
  bf16x8 aLo[4][2], aHi[4][2], bLo[2][2], bHi[2][2];
  const int sa = li & 7;
  const int arow = wr * 128 + li;
  const int brow = wc * 64 + li;
  const bool pf = (t + 2 < NT);

  // ---- pre-phase: read aLo (A rows mi0-3) + bLo (B ni0-1)
#pragma unroll
  for (int mi = 0; mi < 4; mi++)
#pragma unroll
    for (int ks = 0; ks < 2; ks++)
      aLo[mi][ks] = *(const bf16x8*)&la[(arow + mi * 16) * 64 + (((ks * 4 + lg) ^ sa) * 8)];
#pragma unroll
  for (int ni = 0; ni < 2; ni++)
#pragma unroll
    for (int ks = 0; ks < 2; ks++)
      bLo[ni][ks] = *(const bf16x8*)&lb[(brow + ni * 16) * 64 + (((ks * 4 + lg) ^ sa) * 8)];
  bar();

  // ---- phase 1: prefetch bHi; MFMA aLo x bLo
#pragma unroll
  for (int ni = 0; ni < 2; ni++)
#pragma unroll
    for (int ks = 0; ks < 2; ks++)
      bHi[ni][ks] = *(const bf16x8*)&lb[(brow + (ni + 2) * 16) * 64 + (((ks * 4 + lg) ^ sa) * 8)];
  __builtin_amdgcn_s_setprio(1);
#pragma unroll
  for (int mi = 0; mi < 4; mi++)
#pragma unroll
    for (int ni = 0; ni < 2; ni++)
#pragma unroll
      for (int ks = 0; ks < 2; ks++)
        acc[mi][ni] = MFMA16(aLo[mi][ks], bLo[ni][ks], acc[mi][ni]);
  __builtin_amdgcn_s_setprio(0);
  barsched();   // ph1 close: A chunks {0,2} fully consumed
  if (pf) {
    stage_chunk(ga, Kst, t + 2, la, 0, rr, gsw, w);
    stage_chunk(ga, Kst, t + 2, la, 2, rr, gsw, w);
  }
  bar();

  // ---- phase 2: prefetch aHi; MFMA aLo x bHi
#pragma unroll
  for (int mi = 0; mi < 4; mi++)
#pragma unroll
    for (int ks = 0; ks < 2; ks++)
      aHi[mi][ks] = *(const bf16x8*)&la[(arow + (mi + 4) * 16) * 64 + (((ks * 4 + lg) ^ sa) * 8)];
  __builtin_amdgcn_s_setprio(1);
#pragma unroll
  for (int mi = 0; mi < 4; mi++)
#pragma unroll
    for (int ni = 0; ni < 2; ni++)
#pragma unroll
      for (int ks = 0; ks < 2; ks++)
        acc[mi][ni + 2] = MFMA16(aLo[mi][ks], bHi[ni][ks], acc[mi][ni + 2]);
  __builtin_amdgcn_s_setprio(0);
  barsched();   // ph2 close: B fully consumed (bHi drained by its MFMAs)
  if (pf) {
    stage_chunk(gb, Kst, t + 2, lb, 0, rr, gsw, w);
    stage_chunk(gb, Kst, t + 2, lb, 1, rr, gsw, w);
  }
  bar();

  // ---- phase 3: MFMA aHi x bLo (operands in regs)
  __builtin_amdgcn_s_setprio(1);
#pragma unroll
  for (int mi = 0; mi < 4; mi++)
#pragma unroll
    for (int ni = 0; ni < 2; ni++)
#pragma unroll
      for (int ks = 0; ks < 2; ks++)
        acc[mi + 4][ni] = MFMA16(aHi[mi][ks], bLo[ni][ks], acc[mi + 4][ni]);
  __builtin_amdgcn_s_setprio(0);
  barsched();   // ph3 close: A fully consumed (aHi drained by its MFMAs)
  if (pf) {
    stage_chunk(gb, Kst, t + 2, lb, 2, rr, gsw, w);
    stage_chunk(gb, Kst, t + 2, lb, 3, rr, gsw, w);
    stage_chunk(ga, Kst, t + 2, la, 1, rr, gsw, w);
    stage_chunk(ga, Kst, t + 2, la, 3, rr, gsw, w);
  }

  // ---- phase 4: MFMA aHi x bHi
  __builtin_amdgcn_s_setprio(1);
#pragma unroll
  for (int mi = 0; mi < 4; mi++)
#pragma unroll
    for (int ni = 0; ni < 2; ni++)
#pragma unroll
      for (int ks = 0; ks < 2; ks++)
        acc[mi + 4][ni + 2] = MFMA16(aHi[mi][ks], bHi[ni][ks], acc[mi + 4][ni + 2]);
  __builtin_amdgcn_s_setprio(0);

  // retire tile t+1's loads; leave t+2's 8 in flight (counted vmcnt, T4)
  if (pf) vwait8(); else vwait0();
  bar();
}

template <int MODE>
__global__ __launch_bounds__(512, 2) void gemm256(
    const __bf16* __restrict__ A, const __bf16* __restrict__ Bt,
    const float* __restrict__ bias, int K, int Ncols,
    __bf16* __restrict__ qo, __bf16* __restrict__ ko, __bf16* __restrict__ vo,
    float* __restrict__ outf) {
  __shared__ __align__(16) __bf16 lds[65536];
  const int tid = threadIdx.x;
  const int w = tid >> 6, lane = tid & 63;
  const int wr = w >> 2, wc = w & 3;
  const int lg = lane >> 4, li = lane & 15;
  // 2D-chunked XCD map (T1)
  const int nbx = gridDim.x;
  const int orig = (int)blockIdx.y * nbx + (int)blockIdx.x;
  const int x = orig & 7, i = orig >> 3;
  const int xc = x & 1, xr = x >> 1;
  const int hw = nbx >> 1;
  const int band = i >> 5;
  const int j = i & 31;
  const size_t n0 = (size_t)(xc * hw + band * 4 + (j & 3)) * 256;
  const size_t m0 = (size_t)(xr * 8 + (j >> 2)) * 256;
  const int rr = tid >> 3;
  const int gsw = ((tid & 7) ^ (rr & 7)) * 8;
  const __bf16* ga = A + m0 * K;
  const __bf16* gb = Bt + n0 * K;
  const int NT = K >> 6;

  __bf16* la0 = lds;
  __bf16* la1 = lds + 16384;
  __bf16* lb0 = lds + 32768;
  __bf16* lb1 = lds + 49152;

  f32x4 acc[8][4] = {};

  stage_tile(ga, K, 0, la0, rr, gsw, w);
  stage_tile(gb, K, 0, lb0, rr, gsw, w);
  stage_tile(ga, K, 1, la1, rr, gsw, w);
  stage_tile(gb, K, 1, lb1, rr, gsw, w);
  vwait8();
  bar();

  for (int t = 0; t < NT; t += 2) {
    tile_step(la0, lb0, acc, ga, gb, K, t,     NT, rr, gsw, w, wr, wc, lg, li);
    tile_step(la1, lb1, acc, ga, gb, K, t + 1, NT, rr, gsw, w, wr, wc, lg, li);
  }

  if (MODE == 0) {
    const int which = (int)(n0 >> 11);            // 0=q 1=k 2=v
    const int b = (int)(m0 >> 11);
    const int mloc = (int)m0 & 2047;              // T index within batch
    if (which == 2) {
      // ---- V^T store via LDS staging (2 passes over wc parity) ----
      __bf16* vt = lds;
#pragma unroll
      for (int p = 0; p < 2; p++) {
        if ((wc & 1) == p) {
          const int rbase = (wc >> 1) * 64 + li;
#pragma unroll
          for (int ni = 0; ni < 4; ni++) {
            const float bv = bias[(int)n0 + wc * 64 + ni * 16 + li];
            const int row = rbase + ni * 16;
#pragma unroll
            for (int mi = 0; mi < 8; mi++) {
              const int tt = wr * 128 + mi * 16 + lg * 4;
              union { __bf16 h[4]; u16x4 u; } zz;
#pragma unroll
              for (int r = 0; r < 4; r++) zz.h[r] = (__bf16)(acc[mi][ni][r] + bv);
              *(u16x4*)&vt[row * 264 + tt] = zz.u;
            }
          }
        }
        __syncthreads();   // writer -> reader: full lgkm drain + barrier
        const int row = tid >> 2;
        const int seg = (tid & 3) * 64;
        const int ncolg = (int)n0 + ((row >> 6) * 2 + p) * 64 + (row & 63);
        const int h = (ncolg & 2047) >> 7;
        const int d = ncolg & 127;
        __bf16* dst = vo + (size_t)(b * 16 + h) * (2048 * 128) + (size_t)d * 2048
                      + mloc + seg;
#pragma unroll
        for (int s = 0; s < 8; s++)
          *(bf16x8*)(dst + s * 8) = *(const bf16x8*)&vt[row * 264 + seg + s * 8];
        __syncthreads();   // reader -> next-pass writer
      }
    } else {
      __bf16* outp = (which == 0) ? qo : ko;
      const float scale = (which == 0) ? QK_SCALE : 1.0f;
#pragma unroll
      for (int ni = 0; ni < 4; ni++) {
        const int ncol = (int)n0 + wc * 64 + ni * 16 + li;
        const float bv = bias[ncol];
        const int h = (ncol & 2047) >> 7;
        const int d = ncol & 127;
        const size_t base = (size_t)(b * 16 + h) * (2048 * 128) + d;
#pragma unroll
        for (int mi = 0; mi < 8; mi++)
#pragma unroll
          for (int r = 0; r < 4; r++) {
            const int tt = (mloc + wr * 128 + mi * 16 + lg * 4 + r) & 2047;
            outp[base + (size_t)tt * 128] = (__bf16)((acc[mi][ni][r] + bv) * scale);
          }
      }
    }
  } else {
#pragma unroll
    for (int ni = 0; ni < 4; ni++) {
      const int ncol = (int)n0 + wc * 64 + ni * 16 + li;
      const float bv = bias[ncol];
#pragma unroll
      for (int mi = 0; mi < 8; mi++)
#pragma unroll
        for (int r = 0; r < 4; r++) {
          const size_t mrow = m0 + wr * 128 + mi * 16 + lg * 4 + r;
          outf[mrow * Ncols + ncol] = acc[mi][ni][r] + bv;
        }
    }
  }
}

// ======== causal flash attention: swapped 32x32 QK^T, in-register P ========
// (unchanged from R12 — verified)
DEVFN void attn_stageK(const __bf16* const (&ksrc)[4], int k0, __bf16* Kl, int w) {
#pragma unroll
  for (int i = 0; i < 4; i++)
    gload16(ksrc[i] + (size_t)k0 * 128, Kl + i * 2048 + w * 512);
}
DEVFN void attn_stageV(const __bf16* const (&vsrc)[4], int k0, __bf16* Vl, int w) {
#pragma unroll
  for (int i = 0; i < 4; i++)
    gload16(vsrc[i] + k0, Vl + i * 2048 + w * 512);
}

template <bool DIAG>
DEVFN void attn_tile(int kt, int n, int q0w, int w, int lq, int hi,
                     const __bf16* const (&ksrc)[4], const __bf16* const (&vsrc)[4],
                     __bf16* Kl, __bf16* Vl,
                     const bf16x8 (&qf)[8], f32x16 (&o)[4],
                     float& mref, float& lrow) {
  const int k0 = kt * 64;
  const bool more = (kt + 1 < n);

  vwait4();      // K(kt) landed (V(kt) still in flight)
  barsched();

  // S^T = K * Q  (two 32-key tiles; accumulate in MFMA regs)
  f32x16 sTa = (f32x16)(0.0f), sTb = (f32x16)(0.0f);
  const int ksw = (lq & 7) << 3;
#pragma unroll
  for (int kk = 0; kk < 8; kk++) {
    bf16x8 ka = *(const bf16x8*)&Kl[lq * 128 + ((kk * 16 + hi * 8) ^ ksw)];
    sTa = MFMA32(ka, qf[kk], sTa);
    bf16x8 kb = *(const bf16x8*)&Kl[(32 + lq) * 128 + ((kk * 16 + hi * 8) ^ ksw)];
    sTb = MFMA32(kb, qf[kk], sTb);
  }
  barsched();    // all waves done reading Kl
  if (more) attn_stageK(ksrc, k0 + 64, Kl, w);

  // move to scalar VGPRs once; all softmax below is VGPR-only, literal idx
  float s0[16], s1[16];
#pragma unroll
  for (int r = 0; r < 16; r++) { s0[r] = sTa[r]; s1[r] = sTb[r]; }

  // mask + row-max (q = lane-local)
  float vm0 = -1e30f, vm1 = -1e30f;
#pragma unroll
  for (int r = 0; r < 16; r++) {
    if (DIAG) {
      const int krow = (r & 3) + 8 * (r >> 2) + 4 * hi;
      if (k0 + krow > q0w + lq) s0[r] = -1e30f;
      if (k0 + 32 + krow > q0w + lq) s1[r] = -1e30f;
    }
    if (r & 1) vm1 = fmaxf(vm1, fmaxf(s0[r], s1[r]));
    else       vm0 = fmaxf(vm0, fmaxf(s0[r], s1[r]));
  }
  float vm = fmaxf(vm0, vm1);
  vm = fmaxf(vm, __shfl_xor(vm, 32));

  // defer-max (T13)
  if (__any(vm - mref > 8.0f)) {
    const bool up = vm - mref > 8.0f;
    const float sc = up ? __builtin_amdgcn_exp2f(mref - vm) : 1.0f;
    if (up) mref = vm;
    lrow *= sc;
#pragma unroll
    for (int r = 0; r < 16; r++) {
      const float scr = __shfl(sc, (r & 3) + 8 * (r >> 2) + 4 * hi);
#pragma unroll
      for (int dt = 0; dt < 4; dt++) o[dt][r] *= scr;
    }
  }

  // exp2 in place + row-sum (VGPR, literal idx)
  float p0 = 0.f, p1 = 0.f, p2 = 0.f, p3 = 0.f;
#pragma unroll
  for (int r = 0; r < 16; r++) {
    const float e0 = __builtin_amdgcn_exp2f(s0[r] - mref);
    const float e1 = __builtin_amdgcn_exp2f(s1[r] - mref);
    s0[r] = e0; s1[r] = e1;
    if ((r & 1) == 0) { p0 += e0; p1 += e1; } else { p2 += e0; p3 += e1; }
  }
  float ps = (p0 + p2) + (p1 + p3);
  ps += __shfl_xor(ps, 32);
  lrow += ps;

  // pack P: literal-index packs + branch-free selects (rule #20 safe)
  const bool h1 = (hi != 0);
  const unsigned q00 = pk2(s0[0],  s0[1]),  q01 = pk2(s0[2],  s0[3]);
  const unsigned q02 = pk2(s0[4],  s0[5]),  q03 = pk2(s0[6],  s0[7]);
  const unsigned q04 = pk2(s0[8],  s0[9]),  q05 = pk2(s0[10], s0[11]);
  const unsigned q06 = pk2(s0[12], s0[13]), q07 = pk2(s0[14], s0[15]);
  const unsigned q10 = pk2(s1[0],  s1[1]),  q11 = pk2(s1[2],  s1[3]);
  const unsigned q12 = pk2(s1[4],  s1[5]),  q13 = pk2(s1[6],  s1[7]);
  const unsigned q14 = pk2(s1[8],  s1[9]),  q15 = pk2(s1[10], s1[11]);
  const unsigned q16 = pk2(s1[12], s1[13]), q17 = pk2(s1[14], s1[15]);
  bf16x8 pa[4];
  pa[0] = mk_pa(h1, q00, q01, q02, q03);
  pa[1] = mk_pa(h1, q04, q05, q06, q07);
  pa[2] = mk_pa(h1, q10, q11, q12, q13);
  pa[3] = mk_pa(h1, q14, q15, q16, q17);

  if (more) vwait4(); else vwait0();   // V(kt) landed (K(kt+1) may remain)
  barsched();

  // O += P V
#pragma unroll
  for (int ks = 0; ks < 4; ks++)
#pragma unroll
    for (int dt = 0; dt < 4; dt++) {
      const int d = dt * 32 + lq;
      bf16x8 vf = *(const bf16x8*)&Vl[d * 64 +
                     ((ks * 16 + hi * 8) ^ (((d ^ (d >> 3)) & 7) << 3))];
      o[dt] = MFMA32(pa[ks], vf, o[dt]);
    }
  barsched();    // all waves done reading Vl
  if (more) attn_stageV(vsrc, k0 + 64, Vl, w);
}

DEVFN void attn_run(int qt, int bh, int w, int lq, int hi,
                    const __bf16* qp, __bf16* ob,
                    const __bf16* const (&ksrc)[4], const __bf16* const (&vsrc)[4],
                    __bf16* Kl, __bf16* Vl) {
  const int q0w = qt * 128 + w * 32;
  bf16x8 qf[8];
#pragma unroll
  for (int kk = 0; kk < 8; kk++)
    qf[kk] = *(const bf16x8*)(qp + (size_t)(q0w + lq) * 128 + kk * 16 + hi * 8);

  f32x16 o[4];
  o[0] = (f32x16)(0.0f); o[1] = (f32x16)(0.0f);
  o[2] = (f32x16)(0.0f); o[3] = (f32x16)(0.0f);
  float mref = -1e30f, lrow = 0.f;

  const int n = 2 * qt + 2;
  attn_stageK(ksrc, 0, Kl, w);
  attn_stageV(vsrc, 0, Vl, w);

  for (int kt = 0; kt < n - 2; kt++)
    attn_tile<false>(kt, n, q0w, w, lq, hi, ksrc, vsrc, Kl, Vl, qf, o, mref, lrow);
  attn_tile<true>(n - 2, n, q0w, w, lq, hi, ksrc, vsrc, Kl, Vl, qf, o, mref, lrow);
  attn_tile<true>(n - 1, n, q0w, w, lq, hi, ksrc, vsrc, Kl, Vl, qf, o, mref, lrow);

  const int b = bh >> 4, h = bh & 15;
  const float inv = 1.0f / lrow;
  float invr[16];
#pragma unroll
  for (int r = 0; r < 16; r++)
    invr[r] = __shfl(inv, (r & 3) + 8 * (r >> 2) + 4 * hi);
#pragma unroll
  for (int dt = 0; dt < 4; dt++)
#pragma unroll
    for (int r = 0; r < 16; r++) {
      const int q = q0w + (r & 3) + 8 * (r >> 2) + 4 * hi;
      ob[(size_t)(b * 2048 + q) * 2048 + h * 128 + dt * 32 + lq]
          = (__bf16)(o[dt][r] * invr[r]);
    }
}

__global__ __launch_bounds__(256, 2) void attn_fwd(
    const __bf16* __restrict__ qb, const __bf16* __restrict__ kb,
    const __bf16* __restrict__ vtb, __bf16* __restrict__ ob) {
  __shared__ __align__(16) __bf16 Kl[64 * 128];   // 16KB
  __shared__ __align__(16) __bf16 Vl[128 * 64];   // 16KB
  const int orig = (int)blockIdx.y * 8 + (int)blockIdx.x;
  const int swz = (orig & 7) * 64 + (orig >> 3);
  const int bx = swz & 7;
  const int bh = swz >> 3;
  const int tid = threadIdx.x;
  const int w = tid >> 6, l = tid & 63;
  const int lq = l & 31, hi = l >> 5;
  const int lg = l >> 4;
  const __bf16* qp = qb + (size_t)bh * (2048 * 128);
  const __bf16* kp = kb + (size_t)bh * (2048 * 128);
  const __bf16* vtp = vtb + (size_t)bh * (2048 * 128);

  const __bf16* ksrc[4];
  const __bf16* vsrc[4];
#pragma unroll
  for (int i = 0; i < 4; i++) {
    const int key = i * 16 + w * 4 + lg;
    ksrc[i] = kp + (size_t)key * 128 + 8 * ((l & 15) ^ (key & 7));
    const int d = i * 32 + (tid >> 3);
    const int g = (tid & 7) ^ ((d ^ (d >> 3)) & 7);
    vsrc[i] = vtp + (size_t)d * 2048 + g * 8;
  }

  attn_run(15 - bx, bh, w, lq, hi, qp, ob, ksrc, vsrc, Kl, Vl);
  attn_run(bx,      bh, w, lq, hi, qp, ob, ksrc, vsrc, Kl, Vl);
}

extern "C" void kernel_launch(void* const* d_in, const int* in_sizes, int n_in,
                              void* d_out, int out_size, void* d_ws, size_t ws_size,
                              hipStream_t stream) {
  (void)in_sizes; (void)n_in; (void)out_size; (void)ws_size;
  const float* x     = (const float*)d_in[0];
  const float* w_qkv = (const float*)d_in[1];
  const float* b_qkv = (const float*)d_in[2];
  const float* w_out = (const float*)d_in[3];
  const float* b_out = (const float*)d_in[4];
  float* out = (float*)d_out;
  char* ws = (char*)d_ws;

  // workspace: xb = x-bf16 (QKV A), then attn output (out-proj A).
  // vbuf holds V^T directly (written coalesced via LDS by the QKV epilogue).
  __bf16* xb    = (__bf16*)(ws + 0);           // 33554432
  __bf16* wqkvT = (__bf16*)(ws + 33554432);    // 25165824  w_qkv^T [6144][2048]
  __bf16* qbuf  = (__bf16*)(ws + 58720256);    // 33554432  [B*H][T][hd]
  __bf16* kbuf  = (__bf16*)(ws + 92274688);    // 33554432  [B*H][T][hd]
  __bf16* vbuf  = (__bf16*)(ws + 125829120);   // 33554432  V^T [B*H][hd][T]
  __bf16* woutT = (__bf16*)(ws + 159383552);   // 8388608   w_out^T [2048][2048]

  cvt_f32_bf16<<<8192, 256, 0, stream>>>(x, xb);
  transpose_w<<<dim3(192, 64), 256, 0, stream>>>(w_qkv, wqkvT, 2048, 6144);
  transpose_w<<<dim3(64, 64), 256, 0, stream>>>(w_out, woutT, 2048, 2048);
  gemm256<0><<<dim3(24, 32), 512, 0, stream>>>(xb, wqkvT, b_qkv, 2048, 6144,
                                               qbuf, kbuf, vbuf, nullptr);
  attn_fwd<<<dim3(8, 64), 256, 0, stream>>>(qbuf, kbuf, vbuf, xb);  // xb := attn out
  gemm256<1><<<dim3(8, 32), 512, 0, stream>>>(xb, woutT, b_out, 2048, 2048,
                                              nullptr, nullptr, nullptr, out);
}

// Round 19
// 400.062 us; speedup vs baseline: 1.2771x; 1.2771x over previous
//
#include <hip/hip_runtime.h>
#include <hip/hip_bf16.h>

#define DEVFN static __device__ __forceinline__

typedef __attribute__((ext_vector_type(8))) __bf16 bf16x8;
typedef __attribute__((ext_vector_type(4))) float f32x4;
typedef __attribute__((ext_vector_type(16))) float f32x16;
typedef __attribute__((ext_vector_type(4))) unsigned short u16x4;

#define MFMA16(a, b, c) __builtin_amdgcn_mfma_f32_16x16x32_bf16(a, b, c, 0, 0, 0)
#define MFMA32(a, b, c) __builtin_amdgcn_mfma_f32_32x32x16_bf16(a, b, c, 0, 0, 0)

// async global->LDS, 16B per lane; dest is wave-uniform base + lane*16
DEVFN void gload16(const void* g, void* l) {
  __builtin_amdgcn_global_load_lds((const __attribute__((address_space(1))) void*)g,
                                   (__attribute__((address_space(3))) void*)l, 16, 0, 0);
}

DEVFN void vwait8() { asm volatile("s_waitcnt vmcnt(8)" ::: "memory"); __builtin_amdgcn_sched_barrier(0); }
DEVFN void vwait4() { asm volatile("s_waitcnt vmcnt(4)" ::: "memory"); __builtin_amdgcn_sched_barrier(0); }
DEVFN void vwait0() { asm volatile("s_waitcnt vmcnt(0)" ::: "memory"); __builtin_amdgcn_sched_barrier(0); }
DEVFN void bar()    { __builtin_amdgcn_s_barrier(); }
// raw barrier + sched fence: safe ONLY when no cross-wave ds_write handoff
DEVFN void barsched() { __builtin_amdgcn_s_barrier(); __builtin_amdgcn_sched_barrier(0); }

// pack two f32 -> dword of 2 bf16 (compiler emits cvt_pk)
DEVFN unsigned pk2(float a, float b) {
  union { __bf16 h[2]; unsigned u; } z;
  z.h[0] = (__bf16)a; z.h[1] = (__bf16)b;
  return z.u;
}

// assemble one PV A-fragment from 4 literal-index packs (branch-free selects)
DEVFN bf16x8 mk_pa(bool h1, unsigned lo0, unsigned lo1, unsigned hi0, unsigned hi1) {
  const unsigned sA = h1 ? hi0 : lo0, sB = h1 ? hi1 : lo1;
  const unsigned cA = h1 ? lo0 : hi0, cB = h1 ? lo1 : hi1;
  const unsigned rA = (unsigned)__shfl_xor((int)cA, 32);
  const unsigned rB = (unsigned)__shfl_xor((int)cB, 32);
  union { unsigned u[4]; bf16x8 v; } z;
  z.u[0] = h1 ? rA : sA; z.u[1] = h1 ? rB : sB;
  z.u[2] = h1 ? sA : rA; z.u[3] = h1 ? sB : rB;
  return z.v;
}

// ---------------- f32 -> bf16 convert (vectorized) ----------------
__global__ __launch_bounds__(256) void cvt_f32_bf16(const float* __restrict__ in,
                                                    __bf16* __restrict__ out) {
  size_t i = ((size_t)blockIdx.x * 256 + threadIdx.x) * 8;
  f32x4 a = *(const f32x4*)(in + i);
  f32x4 b = *(const f32x4*)(in + i + 4);
  bf16x8 u;
  u[0] = (__bf16)a[0]; u[1] = (__bf16)a[1]; u[2] = (__bf16)a[2]; u[3] = (__bf16)a[3];
  u[4] = (__bf16)b[0]; u[5] = (__bf16)b[1]; u[6] = (__bf16)b[2]; u[7] = (__bf16)b[3];
  *(bf16x8*)(out + i) = u;
}

// ---------------- transpose f32 [K][N] -> bf16 [N][K] ----------------
__global__ __launch_bounds__(256) void transpose_w(const float* __restrict__ in,
                                                   __bf16* __restrict__ out,
                                                   int K, int N) {
  __shared__ float tile[32][33];
  const int t = threadIdx.x, tx = t & 31, ty = t >> 5;
  const int n0 = blockIdx.x * 32, k0 = blockIdx.y * 32;
#pragma unroll
  for (int r = 0; r < 4; r++)
    tile[ty + r * 8][tx] = in[(size_t)(k0 + ty + r * 8) * N + n0 + tx];
  __syncthreads();
#pragma unroll
  for (int r = 0; r < 4; r++)
    out[(size_t)(n0 + ty + r * 8) * K + k0 + tx] = (__bf16)tile[tx][ty + r * 8];
}

// ===== 256x256 bf16 GEMM: R17 4-phase schedule + LDS-coalesced V^T store ====
#define QK_SCALE 0.12751745f  // (1/sqrt(128)) * log2(e)

DEVFN void stage_tile(const __bf16* gx, size_t Kst, int t, __bf16* ldst,
                      int rr, int gsw, int w) {
#pragma unroll
  for (int j = 0; j < 4; j++)
    gload16(gx + (size_t)(j * 64 + rr) * Kst + (size_t)t * 64 + gsw,
            ldst + j * 4096 + w * 512);
}

DEVFN void stage_chunk(const __bf16* gx, size_t Kst, int t, __bf16* ldst, int j,
                       int rr, int gsw, int w) {
  gload16(gx + (size_t)(j * 64 + rr) * Kst + (size_t)t * 64 + gsw,
          ldst + j * 4096 + w * 512);
}

// Per K-tile: 4 phases x 16 MFMA; stage of tile t+2 spread across phases.
DEVFN void tile_step(__bf16* la, __bf16* lb, f32x4 (&acc)[8][4],
                     const __bf16* ga, const __bf16* gb, size_t Kst, int t, int NT,
                     int rr, int gsw, int w, int wr, int wc, int lg, int li) {
  bf16x8 a[4][2], bl[2][2], br[2][2];
  const int sa = li & 7;
  const int arow = wr * 128 + li;
  const int brow = wc * 64 + li;
  const bool pf = (t + 2 < NT);

  // ---- phase 1: read A(mi0-3) + B(ni0-1); MFMA (mi0-3 x ni0-1)
#pragma unroll
  for (int mi = 0; mi < 4; mi++)
#pragma unroll
    for (int ks = 0; ks < 2; ks++)
      a[mi][ks] = *(const bf16x8*)&la[(arow + mi * 16) * 64 + (((ks * 4 + lg) ^ sa) * 8)];
#pragma unroll
  for (int ni = 0; ni < 2; ni++)
#pragma unroll
    for (int ks = 0; ks < 2; ks++)
      bl[ni][ks] = *(const bf16x8*)&lb[(brow + ni * 16) * 64 + (((ks * 4 + lg) ^ sa) * 8)];
  bar();
  __builtin_amdgcn_s_setprio(1);
#pragma unroll
  for (int mi = 0; mi < 4; mi++)
#pragma unroll
    for (int ni = 0; ni < 2; ni++)
#pragma unroll
      for (int ks = 0; ks < 2; ks++)
        acc[mi][ni] = MFMA16(a[mi][ks], bl[ni][ks], acc[mi][ni]);
  __builtin_amdgcn_s_setprio(0);
  barsched();   // ph1 close: A chunks {0,2} of this buffer are free

  // ---- phase 2: read B(ni2-3); stage A{0,2}; MFMA (mi0-3 x ni2-3)
#pragma unroll
  for (int ni = 0; ni < 2; ni++)
#pragma unroll
    for (int ks = 0; ks < 2; ks++)
      br[ni][ks] = *(const bf16x8*)&lb[(brow + (ni + 2) * 16) * 64 + (((ks * 4 + lg) ^ sa) * 8)];
  if (pf) {
    stage_chunk(ga, Kst, t + 2, la, 0, rr, gsw, w);
    stage_chunk(ga, Kst, t + 2, la, 2, rr, gsw, w);
  }
  bar();
  __builtin_amdgcn_s_setprio(1);
#pragma unroll
  for (int mi = 0; mi < 4; mi++)
#pragma unroll
    for (int ni = 0; ni < 2; ni++)
#pragma unroll
      for (int ks = 0; ks < 2; ks++)
        acc[mi][ni + 2] = MFMA16(a[mi][ks], br[ni][ks], acc[mi][ni + 2]);
  __builtin_amdgcn_s_setprio(0);
  barsched();   // ph2 close: B fully read by all waves

  // ---- phase 3: read A(mi4-7); stage B{0,1}; MFMA (mi4-7 x ni0-1)
#pragma unroll
  for (int mi = 0; mi < 4; mi++)
#pragma unroll
    for (int ks = 0; ks < 2; ks++)
      a[mi][ks] = *(const bf16x8*)&la[(arow + (mi + 4) * 16) * 64 + (((ks * 4 + lg) ^ sa) * 8)];
  if (pf) {
    stage_chunk(gb, Kst, t + 2, lb, 0, rr, gsw, w);
    stage_chunk(gb, Kst, t + 2, lb, 1, rr, gsw, w);
  }
  bar();
  __builtin_amdgcn_s_setprio(1);
#pragma unroll
  for (int mi = 0; mi < 4; mi++)
#pragma unroll
    for (int ni = 0; ni < 2; ni++)
#pragma unroll
      for (int ks = 0; ks < 2; ks++)
        acc[mi + 4][ni] = MFMA16(a[mi][ks], bl[ni][ks], acc[mi + 4][ni]);
  __builtin_amdgcn_s_setprio(0);
  barsched();   // ph3 close: A fully read by all waves

  // ---- phase 4: stage B{2,3} + A{1,3}; MFMA (mi4-7 x ni2-3)
  if (pf) {
    stage_chunk(gb, Kst, t + 2, lb, 2, rr, gsw, w);
    stage_chunk(gb, Kst, t + 2, lb, 3, rr, gsw, w);
    stage_chunk(ga, Kst, t + 2, la, 1, rr, gsw, w);
    stage_chunk(ga, Kst, t + 2, la, 3, rr, gsw, w);
  }
  __builtin_amdgcn_s_setprio(1);
#pragma unroll
  for (int mi = 0; mi < 4; mi++)
#pragma unroll
    for (int ni = 0; ni < 2; ni++)
#pragma unroll
      for (int ks = 0; ks < 2; ks++)
        acc[mi + 4][ni + 2] = MFMA16(a[mi][ks], br[ni][ks], acc[mi + 4][ni + 2]);
  __builtin_amdgcn_s_setprio(0);

  // retire tile t+1's loads; leave t+2's 8 in flight (counted vmcnt, T4)
  if (pf) vwait8(); else vwait0();
  bar();
}

template <int MODE>
__global__ __launch_bounds__(512, 2) void gemm256(
    const __bf16* __restrict__ A, const __bf16* __restrict__ Bt,
    const float* __restrict__ bias, int K, int Ncols,
    __bf16* __restrict__ qo, __bf16* __restrict__ ko, __bf16* __restrict__ vo,
    float* __restrict__ outf) {
  __shared__ __align__(16) __bf16 lds[65536];
  const int tid = threadIdx.x;
  const int w = tid >> 6, lane = tid & 63;
  const int wr = w >> 2, wc = w & 3;
  const int lg = lane >> 4, li = lane & 15;
  // 2D-chunked XCD map (T1)
  const int nbx = gridDim.x;
  const int orig = (int)blockIdx.y * nbx + (int)blockIdx.x;
  const int x = orig & 7, i = orig >> 3;
  const int xc = x & 1, xr = x >> 1;
  const int hw = nbx >> 1;
  const int band = i >> 5;
  const int j = i & 31;
  const size_t n0 = (size_t)(xc * hw + band * 4 + (j & 3)) * 256;
  const size_t m0 = (size_t)(xr * 8 + (j >> 2)) * 256;
  const int rr = tid >> 3;
  const int gsw = ((tid & 7) ^ (rr & 7)) * 8;
  const __bf16* ga = A + m0 * K;
  const __bf16* gb = Bt + n0 * K;
  const int NT = K >> 6;

  __bf16* la0 = lds;
  __bf16* la1 = lds + 16384;
  __bf16* lb0 = lds + 32768;
  __bf16* lb1 = lds + 49152;

  f32x4 acc[8][4] = {};

  stage_tile(ga, K, 0, la0, rr, gsw, w);
  stage_tile(gb, K, 0, lb0, rr, gsw, w);
  stage_tile(ga, K, 1, la1, rr, gsw, w);
  stage_tile(gb, K, 1, lb1, rr, gsw, w);
  vwait8();
  bar();

  for (int t = 0; t < NT; t += 2) {
    tile_step(la0, lb0, acc, ga, gb, K, t,     NT, rr, gsw, w, wr, wc, lg, li);
    tile_step(la1, lb1, acc, ga, gb, K, t + 1, NT, rr, gsw, w, wr, wc, lg, li);
  }

  if (MODE == 0) {
    const int which = (int)(n0 >> 11);            // 0=q 1=k 2=v
    const int b = (int)(m0 >> 11);
    const int mloc = (int)m0 & 2047;              // T index within batch
    if (which == 2) {
      // ---- V^T store via LDS staging (2 passes over wc parity) ----
      __bf16* vt = lds;
#pragma unroll
      for (int p = 0; p < 2; p++) {
        if ((wc & 1) == p) {
          const int rbase = (wc >> 1) * 64 + li;
#pragma unroll
          for (int ni = 0; ni < 4; ni++) {
            const float bv = bias[(int)n0 + wc * 64 + ni * 16 + li];
            const int row = rbase + ni * 16;
#pragma unroll
            for (int mi = 0; mi < 8; mi++) {
              const int tt = wr * 128 + mi * 16 + lg * 4;
              union { __bf16 h[4]; u16x4 u; } zz;
#pragma unroll
              for (int r = 0; r < 4; r++) zz.h[r] = (__bf16)(acc[mi][ni][r] + bv);
              *(u16x4*)&vt[row * 264 + tt] = zz.u;
            }
          }
        }
        __syncthreads();   // writer -> reader: full lgkm drain + barrier
        const int row = tid >> 2;
        const int seg = (tid & 3) * 64;
        const int ncolg = (int)n0 + ((row >> 6) * 2 + p) * 64 + (row & 63);
        const int h = (ncolg & 2047) >> 7;
        const int d = ncolg & 127;
        __bf16* dst = vo + (size_t)(b * 16 + h) * (2048 * 128) + (size_t)d * 2048
                      + mloc + seg;
#pragma unroll
        for (int s = 0; s < 8; s++)
          *(bf16x8*)(dst + s * 8) = *(const bf16x8*)&vt[row * 264 + seg + s * 8];
        __syncthreads();   // reader -> next-pass writer
      }
    } else {
      __bf16* outp = (which == 0) ? qo : ko;
      const float scale = (which == 0) ? QK_SCALE : 1.0f;
#pragma unroll
      for (int ni = 0; ni < 4; ni++) {
        const int ncol = (int)n0 + wc * 64 + ni * 16 + li;
        const float bv = bias[ncol];
        const int h = (ncol & 2047) >> 7;
        const int d = ncol & 127;
        const size_t base = (size_t)(b * 16 + h) * (2048 * 128) + d;
#pragma unroll
        for (int mi = 0; mi < 8; mi++)
#pragma unroll
          for (int r = 0; r < 4; r++) {
            const int tt = (mloc + wr * 128 + mi * 16 + lg * 4 + r) & 2047;
            outp[base + (size_t)tt * 128] = (__bf16)((acc[mi][ni][r] + bv) * scale);
          }
      }
    }
  } else {
#pragma unroll
    for (int ni = 0; ni < 4; ni++) {
      const int ncol = (int)n0 + wc * 64 + ni * 16 + li;
      const float bv = bias[ncol];
#pragma unroll
      for (int mi = 0; mi < 8; mi++)
#pragma unroll
        for (int r = 0; r < 4; r++) {
          const size_t mrow = m0 + wr * 128 + mi * 16 + lg * 4 + r;
          outf[mrow * Ncols + ncol] = acc[mi][ni][r] + bv;
        }
    }
  }
}

// ======== causal flash attention: swapped 32x32 QK^T, in-register P ========
// (unchanged from R12 — verified)
DEVFN void attn_stageK(const __bf16* const (&ksrc)[4], int k0, __bf16* Kl, int w) {
#pragma unroll
  for (int i = 0; i < 4; i++)
    gload16(ksrc[i] + (size_t)k0 * 128, Kl + i * 2048 + w * 512);
}
DEVFN void attn_stageV(const __bf16* const (&vsrc)[4], int k0, __bf16* Vl, int w) {
#pragma unroll
  for (int i = 0; i < 4; i++)
    gload16(vsrc[i] + k0, Vl + i * 2048 + w * 512);
}

template <bool DIAG>
DEVFN void attn_tile(int kt, int n, int q0w, int w, int lq, int hi,
                     const __bf16* const (&ksrc)[4], const __bf16* const (&vsrc)[4],
                     __bf16* Kl, __bf16* Vl,
                     const bf16x8 (&qf)[8], f32x16 (&o)[4],
                     float& mref, float& lrow) {
  const int k0 = kt * 64;
  const bool more = (kt + 1 < n);

  vwait4();      // K(kt) landed (V(kt) still in flight)
  barsched();

  // S^T = K * Q  (two 32-key tiles; accumulate in MFMA regs)
  f32x16 sTa = (f32x16)(0.0f), sTb = (f32x16)(0.0f);
  const int ksw = (lq & 7) << 3;
#pragma unroll
  for (int kk = 0; kk < 8; kk++) {
    bf16x8 ka = *(const bf16x8*)&Kl[lq * 128 + ((kk * 16 + hi * 8) ^ ksw)];
    sTa = MFMA32(ka, qf[kk], sTa);
    bf16x8 kb = *(const bf16x8*)&Kl[(32 + lq) * 128 + ((kk * 16 + hi * 8) ^ ksw)];
    sTb = MFMA32(kb, qf[kk], sTb);
  }
  barsched();    // all waves done reading Kl
  if (more) attn_stageK(ksrc, k0 + 64, Kl, w);

  // move to scalar VGPRs once; all softmax below is VGPR-only, literal idx
  float s0[16], s1[16];
#pragma unroll
  for (int r = 0; r < 16; r++) { s0[r] = sTa[r]; s1[r] = sTb[r]; }

  // mask + row-max (q = lane-local)
  float vm0 = -1e30f, vm1 = -1e30f;
#pragma unroll
  for (int r = 0; r < 16; r++) {
    if (DIAG) {
      const int krow = (r & 3) + 8 * (r >> 2) + 4 * hi;
      if (k0 + krow > q0w + lq) s0[r] = -1e30f;
      if (k0 + 32 + krow > q0w + lq) s1[r] = -1e30f;
    }
    if (r & 1) vm1 = fmaxf(vm1, fmaxf(s0[r], s1[r]));
    else       vm0 = fmaxf(vm0, fmaxf(s0[r], s1[r]));
  }
  float vm = fmaxf(vm0, vm1);
  vm = fmaxf(vm, __shfl_xor(vm, 32));

  // defer-max (T13)
  if (__any(vm - mref > 8.0f)) {
    const bool up = vm - mref > 8.0f;
    const float sc = up ? __builtin_amdgcn_exp2f(mref - vm) : 1.0f;
    if (up) mref = vm;
    lrow *= sc;
#pragma unroll
    for (int r = 0; r < 16; r++) {
      const float scr = __shfl(sc, (r & 3) + 8 * (r >> 2) + 4 * hi);
#pragma unroll
      for (int dt = 0; dt < 4; dt++) o[dt][r] *= scr;
    }
  }

  // exp2 in place + row-sum (VGPR, literal idx)
  float p0 = 0.f, p1 = 0.f, p2 = 0.f, p3 = 0.f;
#pragma unroll
  for (int r = 0; r < 16; r++) {
    const float e0 = __builtin_amdgcn_exp2f(s0[r] - mref);
    const float e1 = __builtin_amdgcn_exp2f(s1[r] - mref);
    s0[r] = e0; s1[r] = e1;
    if ((r & 1) == 0) { p0 += e0; p1 += e1; } else { p2 += e0; p3 += e1; }
  }
  float ps = (p0 + p2) + (p1 + p3);
  ps += __shfl_xor(ps, 32);
  lrow += ps;

  // pack P: literal-index packs + branch-free selects (rule #20 safe)
  const bool h1 = (hi != 0);
  const unsigned q00 = pk2(s0[0],  s0[1]),  q01 = pk2(s0[2],  s0[3]);
  const unsigned q02 = pk2(s0[4],  s0[5]),  q03 = pk2(s0[6],  s0[7]);
  const unsigned q04 = pk2(s0[8],  s0[9]),  q05 = pk2(s0[10], s0[11]);
  const unsigned q06 = pk2(s0[12], s0[13]), q07 = pk2(s0[14], s0[15]);
  const unsigned q10 = pk2(s1[0],  s1[1]),  q11 = pk2(s1[2],  s1[3]);
  const unsigned q12 = pk2(s1[4],  s1[5]),  q13 = pk2(s1[6],  s1[7]);
  const unsigned q14 = pk2(s1[8],  s1[9]),  q15 = pk2(s1[10], s1[11]);
  const unsigned q16 = pk2(s1[12], s1[13]), q17 = pk2(s1[14], s1[15]);
  bf16x8 pa[4];
  pa[0] = mk_pa(h1, q00, q01, q02, q03);
  pa[1] = mk_pa(h1, q04, q05, q06, q07);
  pa[2] = mk_pa(h1, q10, q11, q12, q13);
  pa[3] = mk_pa(h1, q14, q15, q16, q17);

  if (more) vwait4(); else vwait0();   // V(kt) landed (K(kt+1) may remain)
  barsched();

  // O += P V
#pragma unroll
  for (int ks = 0; ks < 4; ks++)
#pragma unroll
    for (int dt = 0; dt < 4; dt++) {
      const int d = dt * 32 + lq;
      bf16x8 vf = *(const bf16x8*)&Vl[d * 64 +
                     ((ks * 16 + hi * 8) ^ (((d ^ (d >> 3)) & 7) << 3))];
      o[dt] = MFMA32(pa[ks], vf, o[dt]);
    }
  barsched();    // all waves done reading Vl
  if (more) attn_stageV(vsrc, k0 + 64, Vl, w);
}

DEVFN void attn_run(int qt, int bh, int w, int lq, int hi,
                    const __bf16* qp, __bf16* ob,
                    const __bf16* const (&ksrc)[4], const __bf16* const (&vsrc)[4],
                    __bf16* Kl, __bf16* Vl) {
  const int q0w = qt * 128 + w * 32;
  bf16x8 qf[8];
#pragma unroll
  for (int kk = 0; kk < 8; kk++)
    qf[kk] = *(const bf16x8*)(qp + (size_t)(q0w + lq) * 128 + kk * 16 + hi * 8);

  f32x16 o[4];
  o[0] = (f32x16)(0.0f); o[1] = (f32x16)(0.0f);
  o[2] = (f32x16)(0.0f); o[3] = (f32x16)(0.0f);
  float mref = -1e30f, lrow = 0.f;

  const int n = 2 * qt + 2;
  attn_stageK(ksrc, 0, Kl, w);
  attn_stageV(vsrc, 0, Vl, w);

  for (int kt = 0; kt < n - 2; kt++)
    attn_tile<false>(kt, n, q0w, w, lq, hi, ksrc, vsrc, Kl, Vl, qf, o, mref, lrow);
  attn_tile<true>(n - 2, n, q0w, w, lq, hi, ksrc, vsrc, Kl, Vl, qf, o, mref, lrow);
  attn_tile<true>(n - 1, n, q0w, w, lq, hi, ksrc, vsrc, Kl, Vl, qf, o, mref, lrow);

  const int b = bh >> 4, h = bh & 15;
  const float inv = 1.0f / lrow;
  float invr[16];
#pragma unroll
  for (int r = 0; r < 16; r++)
    invr[r] = __shfl(inv, (r & 3) + 8 * (r >> 2) + 4 * hi);
#pragma unroll
  for (int dt = 0; dt < 4; dt++)
#pragma unroll
    for (int r = 0; r < 16; r++) {
      const int q = q0w + (r & 3) + 8 * (r >> 2) + 4 * hi;
      ob[(size_t)(b * 2048 + q) * 2048 + h * 128 + dt * 32 + lq]
          = (__bf16)(o[dt][r] * invr[r]);
    }
}

__global__ __launch_bounds__(256, 2) void attn_fwd(
    const __bf16* __restrict__ qb, const __bf16* __restrict__ kb,
    const __bf16* __restrict__ vtb, __bf16* __restrict__ ob) {
  __shared__ __align__(16) __bf16 Kl[64 * 128];   // 16KB
  __shared__ __align__(16) __bf16 Vl[128 * 64];   // 16KB
  const int orig = (int)blockIdx.y * 8 + (int)blockIdx.x;
  const int swz = (orig & 7) * 64 + (orig >> 3);
  const int bx = swz & 7;
  const int bh = swz >> 3;
  const int tid = threadIdx.x;
  const int w = tid >> 6, l = tid & 63;
  const int lq = l & 31, hi = l >> 5;
  const int lg = l >> 4;
  const __bf16* qp = qb + (size_t)bh * (2048 * 128);
  const __bf16* kp = kb + (size_t)bh * (2048 * 128);
  const __bf16* vtp = vtb + (size_t)bh * (2048 * 128);

  const __bf16* ksrc[4];
  const __bf16* vsrc[4];
#pragma unroll
  for (int i = 0; i < 4; i++) {
    const int key = i * 16 + w * 4 + lg;
    ksrc[i] = kp + (size_t)key * 128 + 8 * ((l & 15) ^ (key & 7));
    const int d = i * 32 + (tid >> 3);
    const int g = (tid & 7) ^ ((d ^ (d >> 3)) & 7);
    vsrc[i] = vtp + (size_t)d * 2048 + g * 8;
  }

  attn_run(15 - bx, bh, w, lq, hi, qp, ob, ksrc, vsrc, Kl, Vl);
  attn_run(bx,      bh, w, lq, hi, qp, ob, ksrc, vsrc, Kl, Vl);
}

extern "C" void kernel_launch(void* const* d_in, const int* in_sizes, int n_in,
                              void* d_out, int out_size, void* d_ws, size_t ws_size,
                              hipStream_t stream) {
  (void)in_sizes; (void)n_in; (void)out_size; (void)ws_size;
  const float* x     = (const float*)d_in[0];
  const float* w_qkv = (const float*)d_in[1];
  const float* b_qkv = (const float*)d_in[2];
  const float* w_out = (const float*)d_in[3];
  const float* b_out = (const float*)d_in[4];
  float* out = (float*)d_out;
  char* ws = (char*)d_ws;

  // workspace: xb = x-bf16 (QKV A), then attn output (out-proj A).
  // vbuf holds V^T directly (written coalesced via LDS by the QKV epilogue).
  __bf16* xb    = (__bf16*)(ws + 0);           // 33554432
  __bf16* wqkvT = (__bf16*)(ws + 33554432);    // 25165824  w_qkv^T [6144][2048]
  __bf16* qbuf  = (__bf16*)(ws + 58720256);    // 33554432  [B*H][T][hd]
  __bf16* kbuf  = (__bf16*)(ws + 92274688);    // 33554432  [B*H][T][hd]
  __bf16* vbuf  = (__bf16*)(ws + 125829120);   // 33554432  V^T [B*H][hd][T]
  __bf16* woutT = (__bf16*)(ws + 159383552);   // 8388608   w_out^T [2048][2048]

  cvt_f32_bf16<<<8192, 256, 0, stream>>>(x, xb);
  transpose_w<<<dim3(192, 64), 256, 0, stream>>>(w_qkv, wqkvT, 2048, 6144);
  transpose_w<<<dim3(64, 64), 256, 0, stream>>>(w_out, woutT, 2048, 2048);
  gemm256<0><<<dim3(24, 32), 512, 0, stream>>>(xb, wqkvT, b_qkv, 2048, 6144,
                                               qbuf, kbuf, vbuf, nullptr);
  attn_fwd<<<dim3(8, 64), 256, 0, stream>>>(qbuf, kbuf, vbuf, xb);  // xb := attn out
  gemm256<1><<<dim3(8, 32), 512, 0, stream>>>(xb, woutT, b_out, 2048, 2048,
                                              nullptr, nullptr, nullptr, out);
}